// Round 4
// baseline (227.474 us; speedup 1.0000x reference)
//
#include <hip/hip_runtime.h>
#include <hip/hip_bf16.h>
#include <stdint.h>

// LePEAttention via MFMA, per-head blocks for occupancy.
// B=4, C=64, H=W=128, heads=8, hd=8, window=128x2 (256 toks).
// Grid 2048 = (b, head, wi): one block = one head of one window. 256 thr = 4 waves,
// each wave owns 4 query-strips (16 queries each). LDS 19.1KB -> 8 blocks/CU.

typedef __attribute__((ext_vector_type(8))) short bf16x8;
typedef __attribute__((ext_vector_type(4))) float f32x4;

static __device__ __forceinline__ uint32_t pk2(float x, float y) {
    union { __hip_bfloat162 h2; uint32_t u; } c;
    c.h2 = __float22bfloat162_rn(make_float2(x, y));
    return c.u;
}

__global__ __launch_bounds__(256, 6)
void lepe_attn(const float* __restrict__ temp,
               const float* __restrict__ conv_w,
               const float* __restrict__ conv_b,
               float* __restrict__ out)
{
    // k_b: [256 tok][24B] (8 ch bf16 + 8B pad; 6*lr mod 32 distinct -> conflict-free b128)
    // v_b: [8 ch][536B]   (260+ tok bf16, pad for bank spread)
    // p_b: 4 waves x (16 rows x 136B) P buffers; doubles as Q staging (256x24B) first.
    __shared__ __align__(16) char smem[19136];
    char* k_b  = smem;
    char* v_b  = smem + 6144;
    char* p_b0 = smem + 10432;

    const int tid  = threadIdx.x;
    const int wave = tid >> 6, lane = tid & 63;
    const int lr = lane & 15, g = lane >> 4;
    const int dd = lane & 7;

    // bid -> (XCD-octet) swizzle: XCD = bid&7 owns wi in [8x, 8x+8).
    const int bid = blockIdx.x;
    const int x = bid & 7, y = bid >> 3;
    const int wj   = y & 7;
    const int head = (y >> 3) & 7;
    const int b    = y >> 6;
    const int wi   = x * 8 + wj;
    const int c0   = head * 8;

    const size_t cstr = 16384, sstr = 64 * cstr;
    const float qs = 0.35355339059327373f * 1.4426950408889634f; // hd^-0.5 * log2e

    // ---- staging: thread (cg=tid&7 chan, hh0=tid>>3 row-group) ----
    const int cg = tid & 7, hh0 = tid >> 3;
    {
        const float* qp = temp + (size_t)b * 3 * sstr + (size_t)(c0 + cg) * cstr + wi * 2;
        const float* kp = qp + sstr;
        const float* vp = qp + 2 * sstr;
        char* q_s = p_b0;   // Q staged in P region, stride 24B
        #pragma unroll
        for (int i = 0; i < 4; ++i) {
            int h = i * 32 + hh0;
            float2 f = *(const float2*)(qp + h * 128);
            uint32_t pq = pk2(f.x * qs, f.y * qs);
            *(uint16_t*)(q_s + (2 * h) * 24 + cg * 2)     = (uint16_t)pq;
            *(uint16_t*)(q_s + (2 * h + 1) * 24 + cg * 2) = (uint16_t)(pq >> 16);
            float2 fk = *(const float2*)(kp + h * 128);
            uint32_t pkk = pk2(fk.x, fk.y);
            *(uint16_t*)(k_b + (2 * h) * 24 + cg * 2)     = (uint16_t)pkk;
            *(uint16_t*)(k_b + (2 * h + 1) * 24 + cg * 2) = (uint16_t)(pkk >> 16);
            float2 fv = *(const float2*)(vp + h * 128);
            *(uint32_t*)(v_b + cg * 536 + h * 4) = pk2(fv.x, fv.y);
        }
    }

    // conv weights/bias -> regs (channel c0+dd; lanes lr>=8 duplicate)
    float cwr[9];
    #pragma unroll
    for (int t = 0; t < 9; ++t) cwr[t] = conv_w[(c0 + dd) * 9 + t];
    const float cbr = conv_b[c0 + dd];

    __syncthreads();

    // ---- Q A-frags: this wave's 4 strips (lanes>=16 zero; row = 8 bf16 = 16B) ----
    const uint4 z4 = make_uint4(0, 0, 0, 0);
    uint4 qf[4];
    #pragma unroll
    for (int j = 0; j < 4; ++j) {
        int s = wave * 4 + j;
        uint4 t = *(const uint4*)(p_b0 + (s * 16 + lr) * 24);
        qf[j] = (lane < 16) ? t : z4;
    }
    __syncthreads();   // Q region now reusable as P buffers

    char* p_b = p_b0 + wave * 2176;   // wave-private 16 rows x 136B
    const f32x4 zf = {0.f, 0.f, 0.f, 0.f};
    const size_t obase = (size_t)b * 1048576 + (size_t)wi * 128 + c0 + lr;

    #pragma unroll 1
    for (int j = 0; j < 4; ++j) {
        const int s = wave * 4 + j;
        f32x4 o = zf;
        float rs0 = 0.f, rs1 = 0.f, rs2 = 0.f, rs3 = 0.f;
        union { uint4 u; bf16x8 h; } qa; qa.u = qf[j];

        #pragma unroll
        for (int c4 = 0; c4 < 4; ++c4) {
            // 4 QK tiles (keys c4*64 .. +63): B-frag = K rows (16 toks x 8 ch)
            f32x4 sc[4];
            #pragma unroll
            for (int t = 0; t < 4; ++t) {
                uint4 kb = *(const uint4*)(k_b + (c4 * 64 + t * 16 + lr) * 24);
                union { uint4 u; bf16x8 h; } kf; kf.u = (lane < 16) ? kb : z4;
                sc[t] = __builtin_amdgcn_mfma_f32_16x16x32_bf16(qa.h, kf.h, zf, 0, 0, 0);
            }
            // exp2, rowsum, P -> LDS (rows = query 4g+r, cols = key 16t+lr)
            #pragma unroll
            for (int t = 0; t < 4; ++t) {
                float e0 = __builtin_amdgcn_exp2f(sc[t][0]);
                float e1 = __builtin_amdgcn_exp2f(sc[t][1]);
                float e2 = __builtin_amdgcn_exp2f(sc[t][2]);
                float e3 = __builtin_amdgcn_exp2f(sc[t][3]);
                rs0 += e0; rs1 += e1; rs2 += e2; rs3 += e3;
                uint32_t p01 = pk2(e0, e1), p23 = pk2(e2, e3);
                char* pb = p_b + (16 * t + lr) * 2;
                *(uint16_t*)(pb + (4 * g + 0) * 136) = (uint16_t)p01;
                *(uint16_t*)(pb + (4 * g + 1) * 136) = (uint16_t)(p01 >> 16);
                *(uint16_t*)(pb + (4 * g + 2) * 136) = (uint16_t)p23;
                *(uint16_t*)(pb + (4 * g + 3) * 136) = (uint16_t)(p23 >> 16);
            }
            // 2 PV mfma: A = P(16q x 32k), B = V[key][ch] (cols>=8 zero)
            #pragma unroll
            for (int kk = 0; kk < 2; ++kk) {
                uint4 pa = *(const uint4*)(p_b + lr * 136 + kk * 64 + g * 16);
                uint4 vb = *(const uint4*)(v_b + dd * 536 + c4 * 128 + kk * 64 + g * 16);
                union { uint4 u; bf16x8 h; } paf, vbf;
                paf.u = pa;
                vbf.u = (lr < 8) ? vb : z4;
                o = __builtin_amdgcn_mfma_f32_16x16x32_bf16(paf.h, vbf.h, o, 0, 0, 0);
            }
        }
        // rowsum across the 16-lane column group
        #pragma unroll
        for (int m = 1; m < 16; m <<= 1) {
            rs0 += __shfl_xor(rs0, m);
            rs1 += __shfl_xor(rs1, m);
            rs2 += __shfl_xor(rs2, m);
            rs3 += __shfl_xor(rs3, m);
        }
        if (lr < 8) {
            // LePE conv taps: toks 16s+4g-2 .. +5, channel c0+lr, zero outside window
            float tv[8];
            const int base_tok = s * 16 + 4 * g - 2;
            #pragma unroll
            for (int t = 0; t < 8; ++t) {
                int tok = base_tok + t;
                int tc = tok < 0 ? 0 : (tok > 255 ? 255 : tok);
                union { uint16_t u; __hip_bfloat16 h2; } lv;
                lv.u = *(const uint16_t*)(v_b + lr * 536 + tc * 2);
                float val = __bfloat162float(lv.h2);
                tv[t] = (tok == tc) ? val : 0.f;
            }
            float rsv[4] = {rs0, rs1, rs2, rs3};
            #pragma unroll
            for (int r = 0; r < 4; ++r) {
                int w01 = r & 1;
                float rp = cbr;
                #pragma unroll
                for (int dy = 0; dy < 3; ++dy) {
                    #pragma unroll
                    for (int wp = 0; wp < 2; ++wp)
                        rp = fmaf(cwr[dy * 3 + (wp + 1 - w01)], tv[2 * (r >> 1) + 2 * dy + wp], rp);
                }
                int tok = s * 16 + 4 * g + r;
                out[obase + (size_t)(tok >> 1) * 8192 + (size_t)(tok & 1) * 64] = o[r] / rsv[r] + rp;
            }
        }
    }
}

extern "C" void kernel_launch(void* const* d_in, const int* in_sizes, int n_in,
                              void* d_out, int out_size, void* d_ws, size_t ws_size,
                              hipStream_t stream) {
    const float* temp = (const float*)d_in[0];
    const float* cw   = (const float*)d_in[1];
    const float* cb   = (const float*)d_in[2];
    float* o = (float*)d_out;
    (void)in_sizes; (void)n_in; (void)out_size; (void)d_ws; (void)ws_size;
    lepe_attn<<<dim3(2048), dim3(256), 0, stream>>>(temp, cw, cb, o);
}

// Round 5
// 220.256 us; speedup vs baseline: 1.0328x; 1.0328x over previous
//
#include <hip/hip_runtime.h>
#include <hip/hip_bf16.h>
#include <stdint.h>

// LePEAttention hybrid: MFMA QK^T + register-resident scalar PV (no P round-trip).
// B=4, C=64, H=W=128, heads=8, hd=8, window=128x2 (256 toks).
// Grid 2048 = (b, head, wi); 256 thr = 4 waves, wave owns 4 query-strips (16 q each).
// C-layout fact (verified r3/r4): lane (q=lane>>4, lr=lane&15) holds S[query 4q+r][key lr].
// PV: per 16-key tile, lane reads V[key=16T+lr] (quad-broadcast) and FMAs into
// acc[r][d]; per-strip 16-lane splitting-butterfly reduce distributes results so
// lane ends with (query r_f, channel pair d0) -> 8B paired stores.

typedef __attribute__((ext_vector_type(8))) short bf16x8;
typedef __attribute__((ext_vector_type(4))) float f32x4;

static __device__ __forceinline__ uint32_t pk2(float x, float y) {
    union { __hip_bfloat162 h2; uint32_t u; } c;
    c.h2 = __float22bfloat162_rn(make_float2(x, y));
    return c.u;
}
static __device__ __forceinline__ float bflo(uint32_t u) { return __uint_as_float(u << 16); }
static __device__ __forceinline__ float bfhi(uint32_t u) { return __uint_as_float(u & 0xffff0000u); }

__global__ __launch_bounds__(256, 4)
void lepe_attn(const float* __restrict__ temp,
               const float* __restrict__ conv_w,
               const float* __restrict__ conv_b,
               float* __restrict__ out)
{
    __shared__ __align__(16) char smem[16704];
    char* q_s = smem;            // [256 tok][16B] scaled-Q bf16 x 8ch (2-way on frag read)
    char* k_b = smem + 4096;     // [256 tok][24B] K bf16 x 8ch + pad (2-way on frag read)
    char* v_b = smem + 10240;    // [256 tok][24B] V bf16 x 8ch + pad (bcast/2-way reads)
    float* cw_s = (float*)(smem + 16384);  // [8][9] conv w + [8] bias

    const int tid  = threadIdx.x;
    const int wave = tid >> 6, lane = tid & 63;
    const int lr = lane & 15, qd = lane >> 4;

    // XCD swizzle: XCD = bid&7 owns 8 consecutive wi (keeps FETCH near ideal).
    const int bid = blockIdx.x;
    const int x = bid & 7, y = bid >> 3;
    const int wi   = x * 8 + (y & 7);
    const int head = (y >> 3) & 7;
    const int b    = y >> 6;
    const int c0   = head * 8;

    const size_t cstr = 16384, sstr = 64 * cstr;
    const float qs = 0.35355339059327373f * 1.4426950408889634f;  // hd^-0.5 * log2e

    // ---- stage Q(scaled)/K/V as bf16; thread = (ch cg, row-group hh0) ----
    {
        const int cg = tid & 7, hh0 = tid >> 3;   // hh0 0..31
        const float* qp = temp + (size_t)b * 3 * sstr + (size_t)(c0 + cg) * cstr + wi * 2;
        #pragma unroll
        for (int i = 0; i < 4; ++i) {
            int h = i * 32 + hh0;
            float2 fq = *(const float2*)(qp + (size_t)h * 128);
            uint32_t uq = pk2(fq.x * qs, fq.y * qs);
            *(uint16_t*)(q_s + (2 * h) * 16 + cg * 2)     = (uint16_t)uq;
            *(uint16_t*)(q_s + (2 * h + 1) * 16 + cg * 2) = (uint16_t)(uq >> 16);
            float2 fk = *(const float2*)(qp + sstr + (size_t)h * 128);
            uint32_t uk = pk2(fk.x, fk.y);
            *(uint16_t*)(k_b + (2 * h) * 24 + cg * 2)     = (uint16_t)uk;
            *(uint16_t*)(k_b + (2 * h + 1) * 24 + cg * 2) = (uint16_t)(uk >> 16);
            float2 fv = *(const float2*)(qp + 2 * sstr + (size_t)h * 128);
            uint32_t uv = pk2(fv.x, fv.y);
            *(uint16_t*)(v_b + (2 * h) * 24 + cg * 2)     = (uint16_t)uv;
            *(uint16_t*)(v_b + (2 * h + 1) * 24 + cg * 2) = (uint16_t)(uv >> 16);
        }
        if (tid < 80) cw_s[tid] = (tid < 72) ? conv_w[c0 * 9 + tid] : conv_b[c0 + (tid - 72)];
    }
    __syncthreads();

    // ---- per-lane output assignment (from butterfly bit mapping) ----
    const int r_f = ((lr & 1) << 1) | ((lr >> 1) & 1);       // query reg 0..3
    const int d0  = ((lr >> 2) & 1) * 4 + ((lr >> 3) & 1) * 2; // channel pair base
    const int w01 = r_f & 1;

    // conv weights for this lane's 2 channels (strip-independent)
    float wgt[6][2];
    #pragma unroll
    for (int dy = 0; dy < 3; ++dy)
        #pragma unroll
        for (int wp = 0; wp < 2; ++wp) {
            int idx = dy * 3 + (wp + 1 - w01);
            wgt[dy * 2 + wp][0] = cw_s[d0 * 9 + idx];
            wgt[dy * 2 + wp][1] = cw_s[(d0 + 1) * 9 + idx];
        }
    const float bia0 = cw_s[72 + d0], bia1 = cw_s[72 + d0 + 1];

    // ---- Q A-frags for this wave's 4 strips ----
    const uint4 z4 = make_uint4(0, 0, 0, 0);
    const f32x4 zf = {0.f, 0.f, 0.f, 0.f};
    uint4 qf[4];
    #pragma unroll
    for (int jj = 0; jj < 4; ++jj) {
        uint4 t = *(const uint4*)(q_s + ((wave * 4 + jj) * 16 + lr) * 16);
        qf[jj] = (lane < 16) ? t : z4;
    }

    #pragma unroll 1
    for (int jj = 0; jj < 4; ++jj) {
        const int s = wave * 4 + jj;
        union { uint4 u; bf16x8 h; } qa; qa.u = qf[jj];
        float acc[4][8];
        float rsum[4] = {0.f, 0.f, 0.f, 0.f};
        #pragma unroll
        for (int r = 0; r < 4; ++r)
            #pragma unroll
            for (int d = 0; d < 8; ++d) acc[r][d] = 0.f;

        // ---- main: 16 tiles of 16 keys; QK mfma -> exp -> register PV ----
        #pragma unroll 4
        for (int T = 0; T < 16; ++T) {
            const uint4 kb = *(const uint4*)(k_b + (T * 16 + lr) * 24);
            union { uint4 u; bf16x8 h; } kf; kf.u = (lane < 16) ? kb : z4;
            f32x4 sc = __builtin_amdgcn_mfma_f32_16x16x32_bf16(qa.h, kf.h, zf, 0, 0, 0);
            const uint4 vv = *(const uint4*)(v_b + (T * 16 + lr) * 24);
            float vx[8] = { bflo(vv.x), bfhi(vv.x), bflo(vv.y), bfhi(vv.y),
                            bflo(vv.z), bfhi(vv.z), bflo(vv.w), bfhi(vv.w) };
            #pragma unroll
            for (int r = 0; r < 4; ++r) {
                float e = __builtin_amdgcn_exp2f(sc[r]);
                rsum[r] += e;
                #pragma unroll
                for (int d = 0; d < 8; ++d) acc[r][d] = fmaf(e, vx[d], acc[r][d]);
            }
        }

        // ---- splitting butterfly over the 16-lane key dimension ----
        // After 4 steps lane holds j_base=16*lr0+8*lr1+4*lr2+2*lr3 (+1), j=r*8+d.
        float v[32];
        #pragma unroll
        for (int r = 0; r < 4; ++r)
            #pragma unroll
            for (int d = 0; d < 8; ++d) v[r * 8 + d] = acc[r][d];
        #pragma unroll
        for (int st = 0; st < 4; ++st) {
            const int m = 1 << st, half = 16 >> st;
            const bool hi = (lr >> st) & 1;
            #pragma unroll
            for (int i = 0; i < half; ++i) {
                float snd = hi ? v[i] : v[i + half];
                float kp  = hi ? v[i + half] : v[i];
                v[i] = kp + __shfl_xor(snd, m);
            }
        }
        // rowsum: split over masks 1,2 then full over 4,8 -> rsum_orig[r_f] total
        {
            bool hi = lr & 1;
            float s0 = hi ? rsum[0] : rsum[2], k0 = hi ? rsum[2] : rsum[0];
            float s1 = hi ? rsum[1] : rsum[3], k1 = hi ? rsum[3] : rsum[1];
            rsum[0] = k0 + __shfl_xor(s0, 1);
            rsum[1] = k1 + __shfl_xor(s1, 1);
            bool h2 = (lr >> 1) & 1;
            float s2 = h2 ? rsum[0] : rsum[1], k2 = h2 ? rsum[1] : rsum[0];
            rsum[0] = k2 + __shfl_xor(s2, 2);
            rsum[0] += __shfl_xor(rsum[0], 4);
            rsum[0] += __shfl_xor(rsum[0], 8);
        }
        const float rinv = 1.f / rsum[0];

        // ---- LePE conv taps + store (2 consecutive channels, 8B) ----
        const int tok = s * 16 + (qd << 2) + r_f;
        const int h = tok >> 1;
        float lp0 = bia0, lp1 = bia1;
        #pragma unroll
        for (int dy = -1; dy <= 1; ++dy) {
            int hy = h + dy;
            bool ok = (unsigned)hy < 128u;
            int hc = ok ? hy : h;
            float msk = ok ? 1.f : 0.f;
            #pragma unroll
            for (int wp = 0; wp < 2; ++wp) {
                uint32_t uv = *(const uint32_t*)(v_b + (hc * 2 + wp) * 24 + d0 * 2);
                lp0 = fmaf(wgt[(dy + 1) * 2 + wp][0], bflo(uv) * msk, lp0);
                lp1 = fmaf(wgt[(dy + 1) * 2 + wp][1], bfhi(uv) * msk, lp1);
            }
        }
        float o0 = fmaf(v[0], rinv, lp0);
        float o1 = fmaf(v[1], rinv, lp1);
        size_t addr = (size_t)b * 1048576 + (size_t)(h * 128 + wi * 2 + w01) * 64 + c0 + d0;
        *(float2*)(out + addr) = make_float2(o0, o1);
    }
}

extern "C" void kernel_launch(void* const* d_in, const int* in_sizes, int n_in,
                              void* d_out, int out_size, void* d_ws, size_t ws_size,
                              hipStream_t stream) {
    const float* temp = (const float*)d_in[0];
    const float* cw   = (const float*)d_in[1];
    const float* cb   = (const float*)d_in[2];
    float* o = (float*)d_out;
    (void)in_sizes; (void)n_in; (void)out_size; (void)d_ws; (void)ws_size;
    lepe_attn<<<dim3(2048), dim3(256), 0, stream>>>(temp, cw, cb, o);
}

// Round 6
// 131.750 us; speedup vs baseline: 1.7266x; 1.6718x over previous
//
#include <hip/hip_runtime.h>
#include <hip/hip_bf16.h>
#include <stdint.h>

// LePEAttention, fully-chained MFMA version.
// B=4, C=64, H=W=128, heads=8, hd=8, window=128x2 (256 toks).
// Grid 512 = (b, wj, hf, x): block = (b, wi, ch-half), 4 waves = 4 heads,
// ONE WAVE per window-head. S^T via mfma_16x16x32 (A=K,B=Q) -> exp -> pack
// feeds mfma_16x16x16 PV B-operand DIRECTLY (layout identity, no transport).
// K/V frags cached in VGPRs; inner loop has zero LDS ops. LePE conv (rpe)
// precomputed per block into LDS (overlays K staging).

typedef __attribute__((ext_vector_type(8))) short bf16x8;
typedef __attribute__((ext_vector_type(4))) short bf16x4;
typedef __attribute__((ext_vector_type(4))) float f32x4;

static __device__ __forceinline__ uint32_t pk2(float x, float y) {
    union { __hip_bfloat162 h2; uint32_t u; } c;
    c.h2 = __float22bfloat162_rn(make_float2(x, y));
    return c.u;
}
static __device__ __forceinline__ float bflo(uint32_t u){ return __uint_as_float(u<<16); }
static __device__ __forceinline__ float bfhi(uint32_t u){ return __uint_as_float(u & 0xffff0000u); }

static __device__ __forceinline__ f32x4 mfma16x16x16bf16(bf16x4 a, bf16x4 b, f32x4 c) {
#if __has_builtin(__builtin_amdgcn_mfma_f32_16x16x16bf16_1k)
    return __builtin_amdgcn_mfma_f32_16x16x16bf16_1k(a, b, c, 0, 0, 0);
#else
    f32x4 d;
    asm volatile("v_mfma_f32_16x16x16_bf16 %0, %1, %2, %3\n\ts_nop 7\n\ts_nop 7"
                 : "=v"(d) : "v"(a), "v"(b), "v"(c));
    return d;
#endif
}

__global__ __launch_bounds__(256, 2)
void lepe_attn(const float* __restrict__ temp,
               const float* __restrict__ conv_w,
               const float* __restrict__ conv_b,
               float* __restrict__ out)
{
    __shared__ __align__(16) char smem[55328];
    char* q_s = smem;            // [256 tok][72B]: 32ch bf16 + pad (scaled Q)
    char* k_s = smem + 18432;    // [256 tok][72B] K; later rpe bf16 [256 tok][72B]
    char* v_t = smem + 36864;    // [32 ch][536B]: tok t at byte 2t+4, zero-padded ends
    float* cw_s = (float*)(smem + 54016);  // 288 conv w + 32 bias

    const int tid  = threadIdx.x;
    const int wave = tid >> 6, lane = tid & 63;
    const int lr = lane & 15, quad = lane >> 4;

    // bid = ((b*8 + wj)*2 + hf)*8 + x : XCD = x; hf-pair + wi-octet share XCD.
    const int bid = blockIdx.x;
    const int x  = bid & 7;
    int t_ = bid >> 3;
    const int hf = t_ & 1;  t_ >>= 1;
    const int wj = t_ & 7;
    const int b  = t_ >> 3;
    const int wi = x * 8 + wj;
    const int c0 = hf * 32;

    const size_t cstr = 16384, sstr = 64 * cstr;
    const float qs = 0.35355339059327373f * 1.4426950408889634f;  // hd^-0.5 * log2e

    // ---- staging: thread (cg = ch 0..31, hh0 = row-group 0..7) ----
    {
        const int cg = tid & 31, hh0 = tid >> 5;
        const float* qp = temp + (size_t)b*3*sstr + (size_t)(c0+cg)*cstr + wi*2;
        #pragma unroll
        for (int i = 0; i < 16; ++i) {
            int h = i*8 + hh0;
            float2 fq = *(const float2*)(qp + (size_t)h*128);
            uint32_t uq = pk2(fq.x*qs, fq.y*qs);
            *(uint16_t*)(q_s + (2*h)*72   + cg*2) = (uint16_t)uq;
            *(uint16_t*)(q_s + (2*h+1)*72 + cg*2) = (uint16_t)(uq>>16);
            float2 fk = *(const float2*)(qp + sstr + (size_t)h*128);
            uint32_t uk = pk2(fk.x, fk.y);
            *(uint16_t*)(k_s + (2*h)*72   + cg*2) = (uint16_t)uk;
            *(uint16_t*)(k_s + (2*h+1)*72 + cg*2) = (uint16_t)(uk>>16);
            float2 fv = *(const float2*)(qp + 2*sstr + (size_t)h*128);
            *(uint32_t*)(v_t + cg*536 + 4*h + 4) = pk2(fv.x, fv.y);
        }
        for (int j = tid; j < 288; j += 256) cw_s[j] = conv_w[c0*9 + j];
        if (tid < 32) {
            *(uint32_t*)(v_t + tid*536)       = 0;   // toks -2,-1
            *(uint32_t*)(v_t + tid*536 + 516) = 0;   // toks 256,257
            cw_s[288 + tid] = conv_b[c0 + tid];
        }
    }
    __syncthreads();

    // ---- preload K A-frags (16x b128) and V A-frags (16x b64) into VGPRs ----
    const f32x4 zf = {0.f, 0.f, 0.f, 0.f};
    uint4 kf[16]; uint2 vf[16];
    #pragma unroll
    for (int T = 0; T < 16; ++T) {
        uint4 kk = *(const uint4*)(k_s + (T*16 + lr)*72 + wave*16);
        kf[T] = (lane < 16) ? kk : make_uint4(0,0,0,0);
        uint2 vv = *(const uint2*)(v_t + (wave*8 + (lane&7))*536 + 4 + (T*16 + quad*4)*2);
        vf[T] = (lr < 8) ? vv : make_uint2(0,0);
    }
    __syncthreads();   // all K frags read; k_s region now free for rpe

    // ---- rpe = depthwise 3x3 conv of V (window-local), bf16 into k_s ----
    {
        const int ch = tid & 31, seg = tid >> 5;     // 32 toks per thread
        const char* base = v_t + ch*536 + seg*64;    // toks seg*32-2 .. +33
        uint32_t d[18];
        *(uint4*)(d+0)  = *(const uint4*)(base);
        *(uint4*)(d+4)  = *(const uint4*)(base+16);
        *(uint4*)(d+8)  = *(const uint4*)(base+32);
        *(uint4*)(d+12) = *(const uint4*)(base+48);
        *(uint2*)(d+16) = *(const uint2*)(base+64);
        float w9[9];
        #pragma unroll
        for (int k = 0; k < 9; ++k) w9[k] = cw_s[ch*9 + k];
        const float bia = cw_s[288 + ch];
        #pragma unroll
        for (int tt = 0; tt < 32; ++tt) {
            int tok = seg*32 + tt;
            int w01 = tok & 1;
            int L = (tt >> 1) * 2;         // taps = local bf16 idx L..L+5
            float rp = bia;
            #pragma unroll
            for (int dy = 0; dy < 3; ++dy) {
                #pragma unroll
                for (int wp = 0; wp < 2; ++wp) {
                    int idx = L + 2*dy + wp;
                    uint32_t dw = d[idx >> 1];
                    float tap = (idx & 1) ? bfhi(dw) : bflo(dw);
                    rp = fmaf(w9[dy*3 + wp + 1 - w01], tap, rp);
                }
            }
            union { __hip_bfloat16 h; uint16_t u; } cv;
            cv.h = __float2bfloat16(rp);
            *(uint16_t*)(k_s + tok*72 + ch*2) = cv.u;
        }
    }
    __syncthreads();

    // ---- main: per q-group: S^T mfma -> exp -> pack -> PV mfma (chained) ----
    #pragma unroll 1
    for (int qg = 0; qg < 16; ++qg) {
        uint4 qq = *(const uint4*)(q_s + (qg*16 + lr)*72 + wave*16);
        union { uint4 u; bf16x8 h8; } qf; qf.u = (lane < 16) ? qq : make_uint4(0,0,0,0);
        f32x4 acc = zf;
        float rsum = 0.f;
        #pragma unroll
        for (int T = 0; T < 16; ++T) {
            union { uint4 u; bf16x8 h8; } kfu; kfu.u = kf[T];
            f32x4 sc = __builtin_amdgcn_mfma_f32_16x16x32_bf16(kfu.h8, qf.h8, zf, 0, 0, 0);
            float e0 = __builtin_amdgcn_exp2f(sc[0]);
            float e1 = __builtin_amdgcn_exp2f(sc[1]);
            float e2 = __builtin_amdgcn_exp2f(sc[2]);
            float e3 = __builtin_amdgcn_exp2f(sc[3]);
            rsum += (e0 + e1) + (e2 + e3);
            union { uint2 u; bf16x4 h4; } pb; pb.u = make_uint2(pk2(e0,e1), pk2(e2,e3));
            union { uint2 u; bf16x4 h4; } vfu; vfu.u = vf[T];
            acc = mfma16x16x16bf16(vfu.h4, pb.h4, acc);
        }
        float rs = rsum;
        rs += __shfl_xor(rs, 16);
        rs += __shfl_xor(rs, 32);
        const float rinv = __builtin_amdgcn_rcpf(rs);
        if (quad < 2) {
            int tok = qg*16 + lr;
            int h = tok >> 1, w01 = tok & 1;
            uint2 rp2 = *(const uint2*)(k_s + tok*72 + (wave*8 + quad*4)*2);
            float4 ov;
            ov.x = fmaf(acc[0], rinv, bflo(rp2.x));
            ov.y = fmaf(acc[1], rinv, bfhi(rp2.x));
            ov.z = fmaf(acc[2], rinv, bflo(rp2.y));
            ov.w = fmaf(acc[3], rinv, bfhi(rp2.y));
            size_t addr = (size_t)b*1048576 + (size_t)(h*128 + wi*2 + w01)*64
                        + c0 + wave*8 + quad*4;
            *(float4*)(out + addr) = ov;
        }
    }
}

extern "C" void kernel_launch(void* const* d_in, const int* in_sizes, int n_in,
                              void* d_out, int out_size, void* d_ws, size_t ws_size,
                              hipStream_t stream) {
    const float* temp = (const float*)d_in[0];
    const float* cw   = (const float*)d_in[1];
    const float* cb   = (const float*)d_in[2];
    float* o = (float*)d_out;
    (void)in_sizes; (void)n_in; (void)out_size; (void)d_ws; (void)ws_size;
    lepe_attn<<<dim3(512), dim3(256), 0, stream>>>(temp, cw, cb, o);
}